// Round 1
// baseline (1092.200 us; speedup 1.0000x reference)
//
#include <hip/hip_runtime.h>
#include <cstdint>
#include <cstddef>

#define T_TOKENS 4096
#define DIM      1024
#define INTER    1408
#define NEXP     16
#define SINTER   2816

typedef uint32_t u32;
typedef uint16_t u16;

using s8v = __attribute__((ext_vector_type(8))) short;   // 8 bf16 bits in 4 VGPRs
using f4v = __attribute__((ext_vector_type(4))) float;   // MFMA accumulator

__device__ __forceinline__ u16 f2bf(float f) {
  u32 u = __float_as_uint(f);
  u32 r = (u + 0x7fffu + ((u >> 16) & 1u)) >> 16;  // RNE
  return (u16)r;
}
__device__ __forceinline__ u32 pack2(float a, float b) {
  return (u32)f2bf(a) | ((u32)f2bf(b) << 16);
}

// ---------------- Gate: logits -> softmax -> top2 -> bucket counts ----------
__global__ __launch_bounds__(256)
void gate_kernel(const float* __restrict__ x, const float* __restrict__ gw,
                 const float* __restrict__ gb, int* __restrict__ counts,
                 int* __restrict__ g_e, int* __restrict__ g_r, float* __restrict__ g_w)
{
  const int tok  = blockIdx.x * 4 + (threadIdx.x >> 6);
  const int lane = threadIdx.x & 63;
  const float* xr = x + (size_t)tok * DIM;

  float acc[NEXP];
#pragma unroll
  for (int e = 0; e < NEXP; e++) acc[e] = 0.f;

  for (int k = lane; k < DIM; k += 64) {
    float xv = xr[k];
    const float* gwr = gw + k * NEXP;
#pragma unroll
    for (int e = 0; e < NEXP; e++) acc[e] = fmaf(xv, gwr[e], acc[e]);
  }
#pragma unroll
  for (int e = 0; e < NEXP; e++) {
    float v = acc[e];
#pragma unroll
    for (int off = 32; off > 0; off >>= 1) v += __shfl_xor(v, off, 64);
    acc[e] = v + gb[e];
  }
  if (lane == 0) {
    float mx = acc[0];
#pragma unroll
    for (int e = 1; e < NEXP; e++) mx = fmaxf(mx, acc[e]);
    float p[NEXP]; float s = 0.f;
#pragma unroll
    for (int e = 0; e < NEXP; e++) { p[e] = expf(acc[e] - mx); s += p[e]; }
    float inv = 1.f / s;
    int i0 = -1, i1 = -1; float v0 = -1e30f, v1 = -1e30f;
#pragma unroll
    for (int e = 0; e < NEXP; e++) {
      float pe = p[e] * inv;
      if (pe > v0)      { v1 = v0; i1 = i0; v0 = pe; i0 = e; }
      else if (pe > v1) { v1 = pe; i1 = e; }
    }
    int r0 = atomicAdd(&counts[i0], 1);
    int r1 = atomicAdd(&counts[i1], 1);
    g_e[tok * 2 + 0] = i0;  g_e[tok * 2 + 1] = i1;
    g_r[tok * 2 + 0] = r0;  g_r[tok * 2 + 1] = r1;
    g_w[tok * 2 + 0] = v0;  g_w[tok * 2 + 1] = v1;
  }
}

__global__ void scan_kernel(const int* __restrict__ counts, int* __restrict__ offsets) {
  if (threadIdx.x == 0) {
    int s = 0;
#pragma unroll
    for (int e = 0; e < NEXP; e++) { offsets[e] = s; s += counts[e]; }
    offsets[NEXP] = s;
  }
}

__global__ __launch_bounds__(256)
void scatter_kernel(const int* __restrict__ g_e, const int* __restrict__ g_r,
                    const float* __restrict__ g_w, const int* __restrict__ offsets,
                    int* __restrict__ tok_slot, float* __restrict__ w_slot)
{
  int t = blockIdx.x * blockDim.x + threadIdx.x;
  if (t >= T_TOKENS) return;
#pragma unroll
  for (int k = 0; k < 2; k++) {
    int e = g_e[t * 2 + k];
    int slot = offsets[e] + g_r[t * 2 + k];
    tok_slot[slot] = t;
    w_slot[slot] = g_w[t * 2 + k];
  }
}

// ------------- Up projection: act = silu(X@W1 + b1) * (X@W3 + b3) -----------
// 64x64 block tile, BK=32, 4 waves (each wave: 16 rows x 64 cols, dual acc).
template<bool GATHER>
__global__ __launch_bounds__(256)
void ffn_up(const float* __restrict__ x,
            const float* __restrict__ w1p, const float* __restrict__ b1p,
            const float* __restrict__ w3p, const float* __restrict__ b3p,
            int N,
            const int* __restrict__ offsets, const int* __restrict__ tok_slot,
            u16* __restrict__ act)
{
  int e = 0, rowbase = 0, count = T_TOKENS;
  if constexpr (GATHER) {
    e = blockIdx.z;
    rowbase = offsets[e];
    count = offsets[e + 1] - rowbase;
  }
  const int m0 = blockIdx.y * 64;
  if (m0 >= count) return;
  const int n0 = blockIdx.x * 64;

  const float* W1 = w1p + (GATHER ? (size_t)e * DIM * (size_t)N : 0);
  const float* W3 = w3p + (GATHER ? (size_t)e * DIM * (size_t)N : 0);
  const float* B1 = b1p + (GATHER ? (size_t)e * (size_t)N : 0);
  const float* B3 = b3p + (GATHER ? (size_t)e * (size_t)N : 0);

  __shared__ u16 sA[4][64][8];
  __shared__ u16 sB1[4][64][8];
  __shared__ u16 sB3[4][64][8];

  const int tid  = threadIdx.x;
  const int lane = tid & 63;
  const int wave = tid >> 6;
  const int ln   = lane & 15;
  const int q    = lane >> 4;

  // A staging: thread -> (row m_s, k-group kg_s of 8)
  const int m_s  = tid >> 2;
  const int kg_s = tid & 3;
  const int arow = m0 + m_s;
  const bool avalid = arow < count;
  const float* aptr = nullptr;
  if (avalid) {
    int tokr = GATHER ? tok_slot[rowbase + arow] : arow;
    aptr = x + (size_t)tokr * DIM + kg_s * 8;
  }
  // B staging: thread -> (k-row kB, n-group ngB of 8)
  const int kB  = tid >> 3;
  const int ngB = tid & 7;

  f4v acc1[4] = {};
  f4v acc3[4] = {};

  for (int k0 = 0; k0 < DIM; k0 += 32) {
    float4 a0 = make_float4(0, 0, 0, 0), a1 = a0;
    if (avalid) {
      a0 = *(const float4*)(aptr + k0);
      a1 = *(const float4*)(aptr + k0 + 4);
    }
    const float* w1r = W1 + (size_t)(k0 + kB) * N + n0 + ngB * 8;
    float4 b1a = *(const float4*)(w1r);
    float4 b1b = *(const float4*)(w1r + 4);
    const float* w3r = W3 + (size_t)(k0 + kB) * N + n0 + ngB * 8;
    float4 b3a = *(const float4*)(w3r);
    float4 b3b = *(const float4*)(w3r + 4);

    __syncthreads();  // previous iteration's LDS reads complete
    uint4 pk;
    pk.x = pack2(a0.x, a0.y); pk.y = pack2(a0.z, a0.w);
    pk.z = pack2(a1.x, a1.y); pk.w = pack2(a1.z, a1.w);
    *(uint4*)&sA[kg_s][m_s][0] = pk;

    const int bq = kB >> 3, bk = kB & 7;
    u16* d1 = &sB1[bq][ngB * 8][bk];
    d1[0 * 8] = f2bf(b1a.x); d1[1 * 8] = f2bf(b1a.y);
    d1[2 * 8] = f2bf(b1a.z); d1[3 * 8] = f2bf(b1a.w);
    d1[4 * 8] = f2bf(b1b.x); d1[5 * 8] = f2bf(b1b.y);
    d1[6 * 8] = f2bf(b1b.z); d1[7 * 8] = f2bf(b1b.w);
    u16* d3 = &sB3[bq][ngB * 8][bk];
    d3[0 * 8] = f2bf(b3a.x); d3[1 * 8] = f2bf(b3a.y);
    d3[2 * 8] = f2bf(b3a.z); d3[3 * 8] = f2bf(b3a.w);
    d3[4 * 8] = f2bf(b3b.x); d3[5 * 8] = f2bf(b3b.y);
    d3[6 * 8] = f2bf(b3b.z); d3[7 * 8] = f2bf(b3b.w);
    __syncthreads();

    s8v a = *(const s8v*)&sA[q][wave * 16 + ln][0];
#pragma unroll
    for (int c = 0; c < 4; c++) {
      s8v bf1 = *(const s8v*)&sB1[q][c * 16 + ln][0];
      acc1[c] = __builtin_amdgcn_mfma_f32_16x16x32_bf16(a, bf1, acc1[c], 0, 0, 0);
      s8v bf3 = *(const s8v*)&sB3[q][c * 16 + ln][0];
      acc3[c] = __builtin_amdgcn_mfma_f32_16x16x32_bf16(a, bf3, acc3[c], 0, 0, 0);
    }
  }

  float bb1[4], bb3[4];
#pragma unroll
  for (int c = 0; c < 4; c++) {
    bb1[c] = B1[n0 + c * 16 + ln];
    bb3[c] = B3[n0 + c * 16 + ln];
  }
#pragma unroll
  for (int r = 0; r < 4; r++) {
    int row = m0 + wave * 16 + q * 4 + r;   // D row = quad*4 + reg
    if (row >= count) continue;
    u16* actrow = act + (size_t)(rowbase + row) * N;
#pragma unroll
    for (int c = 0; c < 4; c++) {
      int n = n0 + c * 16 + ln;             // D col = lane&15
      float h = acc1[c][r] + bb1[c];
      float g = acc3[c][r] + bb3[c];
      float sig = 1.f / (1.f + __expf(-h));
      actrow[n] = f2bf(h * sig * g);
    }
  }
}

// ------------- Down projection: Y = act @ W2 (+b2), scatter or store --------
template<bool SCATTER>
__global__ __launch_bounds__(256)
void ffn_down(const u16* __restrict__ act, int KA,
              const float* __restrict__ w2p, const float* __restrict__ b2p,
              const int* __restrict__ offsets, const int* __restrict__ tok_slot,
              const float* __restrict__ w_slot,
              float* __restrict__ out)
{
  int e = 0, rowbase = 0, count = T_TOKENS;
  if constexpr (SCATTER) {
    e = blockIdx.z;
    rowbase = offsets[e];
    count = offsets[e + 1] - rowbase;
  }
  const int m0 = blockIdx.y * 64;
  if (m0 >= count) return;
  const int n0 = blockIdx.x * 64;

  const float* W2 = w2p + (SCATTER ? (size_t)e * (size_t)KA * DIM : 0);
  const float* B2 = b2p + (SCATTER ? (size_t)e * DIM : 0);

  __shared__ u16 sA[4][64][8];
  __shared__ u16 sB[4][64][8];

  const int tid  = threadIdx.x;
  const int lane = tid & 63;
  const int wave = tid >> 6;
  const int ln   = lane & 15;
  const int q    = lane >> 4;

  const int m_s  = tid >> 2;
  const int kg_s = tid & 3;
  const int arow = m0 + m_s;
  const bool avalid = arow < count;
  const u16* aptr = avalid ? act + (size_t)(rowbase + arow) * KA + kg_s * 8 : nullptr;

  const int kB  = tid >> 3;
  const int ngB = tid & 7;

  f4v acc[4] = {};

  for (int k0 = 0; k0 < KA; k0 += 32) {
    uint4 av = make_uint4(0, 0, 0, 0);
    if (avalid) av = *(const uint4*)(aptr + k0);
    const float* wr = W2 + (size_t)(k0 + kB) * DIM + n0 + ngB * 8;
    float4 bva = *(const float4*)(wr);
    float4 bvb = *(const float4*)(wr + 4);

    __syncthreads();
    *(uint4*)&sA[kg_s][m_s][0] = av;
    const int bq = kB >> 3, bk = kB & 7;
    u16* d = &sB[bq][ngB * 8][bk];
    d[0 * 8] = f2bf(bva.x); d[1 * 8] = f2bf(bva.y);
    d[2 * 8] = f2bf(bva.z); d[3 * 8] = f2bf(bva.w);
    d[4 * 8] = f2bf(bvb.x); d[5 * 8] = f2bf(bvb.y);
    d[6 * 8] = f2bf(bvb.z); d[7 * 8] = f2bf(bvb.w);
    __syncthreads();

    s8v a = *(const s8v*)&sA[q][wave * 16 + ln][0];
#pragma unroll
    for (int c = 0; c < 4; c++) {
      s8v b = *(const s8v*)&sB[q][c * 16 + ln][0];
      acc[c] = __builtin_amdgcn_mfma_f32_16x16x32_bf16(a, b, acc[c], 0, 0, 0);
    }
  }

  float bb[4];
#pragma unroll
  for (int c = 0; c < 4; c++) bb[c] = B2[n0 + c * 16 + ln];

#pragma unroll
  for (int r = 0; r < 4; r++) {
    int row = m0 + wave * 16 + q * 4 + r;
    if (row >= count) continue;
    if constexpr (SCATTER) {
      int slot = rowbase + row;
      int tok = tok_slot[slot];
      float wgt = w_slot[slot];
      float* orow = out + (size_t)tok * DIM;
#pragma unroll
      for (int c = 0; c < 4; c++) {
        int n = n0 + c * 16 + ln;
        atomicAdd(&orow[n], wgt * (acc[c][r] + bb[c]));
      }
    } else {
      float* orow = out + (size_t)row * DIM;
#pragma unroll
      for (int c = 0; c < 4; c++) {
        int n = n0 + c * 16 + ln;
        orow[n] = acc[c][r] + bb[c];
      }
    }
  }
}

extern "C" void kernel_launch(void* const* d_in, const int* in_sizes, int n_in,
                              void* d_out, int out_size, void* d_ws, size_t ws_size,
                              hipStream_t stream)
{
  const float* x   = (const float*)d_in[0];
  const float* gw  = (const float*)d_in[1];
  const float* gb  = (const float*)d_in[2];
  const float* w1  = (const float*)d_in[3];
  const float* b1  = (const float*)d_in[4];
  const float* w3  = (const float*)d_in[5];
  const float* b3  = (const float*)d_in[6];
  const float* w2  = (const float*)d_in[7];
  const float* b2  = (const float*)d_in[8];
  const float* sw1 = (const float*)d_in[9];
  const float* sb1 = (const float*)d_in[10];
  const float* sw3 = (const float*)d_in[11];
  const float* sb3 = (const float*)d_in[12];
  const float* sw2 = (const float*)d_in[13];
  const float* sb2 = (const float*)d_in[14];
  float* out = (float*)d_out;

  char* ws = (char*)d_ws;
  size_t off = 0;
  auto alloc = [&](size_t bytes) -> char* {
    off = (off + 255) & ~(size_t)255;
    char* p = ws + off;
    off += bytes;
    return p;
  };
  int*   counts   = (int*)  alloc(NEXP * 4);
  int*   offsets  = (int*)  alloc((NEXP + 1) * 4);
  int*   g_e      = (int*)  alloc((size_t)T_TOKENS * 2 * 4);
  int*   g_r      = (int*)  alloc((size_t)T_TOKENS * 2 * 4);
  float* g_w      = (float*)alloc((size_t)T_TOKENS * 2 * 4);
  int*   tok_slot = (int*)  alloc((size_t)T_TOKENS * 2 * 4);
  float* w_slot   = (float*)alloc((size_t)T_TOKENS * 2 * 4);
  u16*   A_act    = (u16*)  alloc((size_t)T_TOKENS * 2 * INTER * 2);
  u16*   S_act    = (u16*)  alloc((size_t)T_TOKENS * SINTER * 2);
  (void)ws_size; (void)in_sizes; (void)n_in; (void)out_size;

  hipMemsetAsync(counts, 0, NEXP * 4, stream);

  gate_kernel<<<T_TOKENS / 4, 256, 0, stream>>>(x, gw, gb, counts, g_e, g_r, g_w);
  scan_kernel<<<1, 64, 0, stream>>>(counts, offsets);
  scatter_kernel<<<T_TOKENS / 256, 256, 0, stream>>>(g_e, g_r, g_w, offsets, tok_slot, w_slot);

  // Shared expert first: plain-stores out = z + sb2 (initializes every element).
  ffn_up<false><<<dim3(SINTER / 64, T_TOKENS / 64, 1), 256, 0, stream>>>(
      x, sw1, sb1, sw3, sb3, SINTER, nullptr, nullptr, S_act);
  ffn_down<false><<<dim3(DIM / 64, T_TOKENS / 64, 1), 256, 0, stream>>>(
      S_act, SINTER, sw2, sb2, nullptr, nullptr, nullptr, out);

  // Routed experts: compacted per-expert GEMMs, then weighted atomic scatter.
  ffn_up<true><<<dim3(INTER / 64, T_TOKENS / 64, NEXP), 256, 0, stream>>>(
      x, w1, b1, w3, b3, INTER, offsets, tok_slot, A_act);
  ffn_down<true><<<dim3(DIM / 64, T_TOKENS / 64, NEXP), 256, 0, stream>>>(
      A_act, INTER, w2, b2, offsets, tok_slot, w_slot, out);
}

// Round 2
// 776.847 us; speedup vs baseline: 1.4059x; 1.4059x over previous
//
#include <hip/hip_runtime.h>
#include <cstdint>
#include <cstddef>

#define T_TOKENS 4096
#define DIM      1024
#define INTER    1408
#define NEXP     16
#define SINTER   2816

typedef uint32_t u32;
typedef uint16_t u16;

using s8v = __attribute__((ext_vector_type(8))) short;   // 8 bf16 (4 VGPRs)
using f4v = __attribute__((ext_vector_type(4))) float;   // MFMA accumulator

__device__ __forceinline__ u16 f2bf(float f) {
  u32 u = __float_as_uint(f);
  return (u16)((u + 0x7fffu + ((u >> 16) & 1u)) >> 16);  // RNE
}
__device__ __forceinline__ u32 pack2(float a, float b) {
  return (u32)f2bf(a) | ((u32)f2bf(b) << 16);
}

// async global->LDS, 16B/lane. LDS dest is wave-uniform base + lane*16.
__device__ __forceinline__ void load_lds16(const u16* g, u16* l) {
  __builtin_amdgcn_global_load_lds((const __attribute__((address_space(1))) void*)g,
                                   (__attribute__((address_space(3))) void*)l,
                                   16, 0, 0);
}

// ---------------- x: fp32 -> bf16 (row-major, elementwise) ------------------
__global__ __launch_bounds__(256)
void cvt_x(const float* __restrict__ in, u16* __restrict__ out) {
  const int i = (blockIdx.x * 256 + threadIdx.x) * 8;
  float4 a = *(const float4*)(in + i);
  float4 b = *(const float4*)(in + i + 4);
  uint4 o;
  o.x = pack2(a.x, a.y); o.y = pack2(a.z, a.w);
  o.z = pack2(b.x, b.y); o.w = pack2(b.z, b.w);
  *(uint4*)(out + i) = o;
}

// ------------- weights: [Z][K][N] fp32 -> [Z][N][K] bf16 (transpose) --------
__global__ __launch_bounds__(256)
void transpose_cvt(const float* __restrict__ in, u16* __restrict__ out,
                   int K, int N) {
  const size_t eoff = (size_t)blockIdx.z * K * N;
  const int n0 = blockIdx.x * 64, k0 = blockIdx.y * 64;
  __shared__ u16 t[64][72];   // row stride 144B = 9*16B: 16B-aligned vector reads

  const int tid = threadIdx.x;
  {
    const int r = tid >> 4, c4 = (tid & 15) * 4;
    const float* src = in + eoff + (size_t)k0 * N + n0;
#pragma unroll
    for (int i = 0; i < 4; i++) {
      int row = r + i * 16;
      float4 v = *(const float4*)(src + (size_t)row * N + c4);
      t[c4 + 0][row] = f2bf(v.x);
      t[c4 + 1][row] = f2bf(v.y);
      t[c4 + 2][row] = f2bf(v.z);
      t[c4 + 3][row] = f2bf(v.w);
    }
  }
  __syncthreads();
  {
    const int r = tid >> 3, cc = (tid & 7) * 8;
    u16* dst = out + eoff + (size_t)n0 * K + k0;
#pragma unroll
    for (int i = 0; i < 2; i++) {
      int row = r + i * 32;
      uint4 v = *(const uint4*)&t[row][cc];
      *(uint4*)(dst + (size_t)row * K + cc) = v;
    }
  }
}

// ---------------- Gate: logits -> softmax -> top2 -> bucket counts ----------
__global__ __launch_bounds__(256)
void gate_kernel(const float* __restrict__ x, const float* __restrict__ gw,
                 const float* __restrict__ gb, int* __restrict__ counts,
                 int* __restrict__ g_e, int* __restrict__ g_r, float* __restrict__ g_w)
{
  const int tok  = blockIdx.x * 4 + (threadIdx.x >> 6);
  const int lane = threadIdx.x & 63;
  const float* xr = x + (size_t)tok * DIM;

  float acc[NEXP];
#pragma unroll
  for (int e = 0; e < NEXP; e++) acc[e] = 0.f;

  for (int k = lane; k < DIM; k += 64) {
    float xv = xr[k];
    const float* gwr = gw + k * NEXP;
#pragma unroll
    for (int e = 0; e < NEXP; e++) acc[e] = fmaf(xv, gwr[e], acc[e]);
  }
#pragma unroll
  for (int e = 0; e < NEXP; e++) {
    float v = acc[e];
#pragma unroll
    for (int off = 32; off > 0; off >>= 1) v += __shfl_xor(v, off, 64);
    acc[e] = v + gb[e];
  }
  if (lane == 0) {
    float mx = acc[0];
#pragma unroll
    for (int e = 1; e < NEXP; e++) mx = fmaxf(mx, acc[e]);
    float p[NEXP]; float s = 0.f;
#pragma unroll
    for (int e = 0; e < NEXP; e++) { p[e] = expf(acc[e] - mx); s += p[e]; }
    float inv = 1.f / s;
    int i0 = -1, i1 = -1; float v0 = -1e30f, v1 = -1e30f;
#pragma unroll
    for (int e = 0; e < NEXP; e++) {
      float pe = p[e] * inv;
      if (pe > v0)      { v1 = v0; i1 = i0; v0 = pe; i0 = e; }
      else if (pe > v1) { v1 = pe; i1 = e; }
    }
    int r0 = atomicAdd(&counts[i0], 1);
    int r1 = atomicAdd(&counts[i1], 1);
    g_e[tok * 2 + 0] = i0;  g_e[tok * 2 + 1] = i1;
    g_r[tok * 2 + 0] = r0;  g_r[tok * 2 + 1] = r1;
    g_w[tok * 2 + 0] = v0;  g_w[tok * 2 + 1] = v1;
  }
}

__global__ void scan_kernel(const int* __restrict__ counts, int* __restrict__ offsets) {
  if (threadIdx.x == 0) {
    int s = 0;
#pragma unroll
    for (int e = 0; e < NEXP; e++) { offsets[e] = s; s += counts[e]; }
    offsets[NEXP] = s;
  }
}

__global__ __launch_bounds__(256)
void scatter_kernel(const int* __restrict__ g_e, const int* __restrict__ g_r,
                    const float* __restrict__ g_w, const int* __restrict__ offsets,
                    int* __restrict__ tok_slot, float* __restrict__ w_slot)
{
  int t = blockIdx.x * blockDim.x + threadIdx.x;
  if (t >= T_TOKENS) return;
#pragma unroll
  for (int k = 0; k < 2; k++) {
    int e = g_e[t * 2 + k];
    int slot = offsets[e] + g_r[t * 2 + k];
    tok_slot[slot] = t;
    w_slot[slot] = g_w[t * 2 + k];
  }
}

// ------------- Up: act = silu(X@W1+b1)*(X@W3+b3), 128x128 tile, BK=32 -------
// A: xbf bf16 row-major (gathered rows for routed). B: wT bf16 [N][K] row-major.
template<bool GATHER>
__global__ __launch_bounds__(256, 2)
void ffn_up2(const u16* __restrict__ xbf,
             const u16* __restrict__ w1t, const float* __restrict__ b1p,
             const u16* __restrict__ w3t, const float* __restrict__ b3p,
             int N,
             const int* __restrict__ offsets, const int* __restrict__ tok_slot,
             u16* __restrict__ act)
{
  int e = 0, rowbase = 0, count = T_TOKENS;
  if constexpr (GATHER) {
    e = blockIdx.z; rowbase = offsets[e]; count = offsets[e + 1] - rowbase;
  }
  const int m0 = blockIdx.y * 128;
  if (m0 >= count) return;
  const int n0 = blockIdx.x * 128;

  const u16* W1 = w1t + (size_t)e * N * DIM;
  const u16* W3 = w3t + (size_t)e * N * DIM;
  const float* B1 = b1p + (size_t)e * N;
  const float* B3 = b3p + (size_t)e * N;

  __shared__ u16 sA[128 * 32];
  __shared__ u16 sB1[128 * 32];
  __shared__ u16 sB3[128 * 32];

  const int tid = threadIdx.x;
  const int lane = tid & 63;
  const int w = tid >> 6;

  // staging: instr i covers rows [i*64 + w*16, +16); lane -> (row, 16B k-chunk)
  const int kc8 = (lane & 3) * 8;
  const u16* aptr[2]; const u16* b1ptr[2]; const u16* b3ptr[2];
  u16 *ldsA[2], *ldsB1[2], *ldsB3[2];
#pragma unroll
  for (int i = 0; i < 2; i++) {
    const int row = i * 64 + w * 16 + (lane >> 2);
    const int ldoff = i * 2048 + w * 512 + lane * 8;   // == row*32 + kc8
    ldsA[i] = sA + ldoff; ldsB1[i] = sB1 + ldoff; ldsB3[i] = sB3 + ldoff;
    int arow = m0 + row; if (arow > count - 1) arow = count - 1;  // clamp pads
    const int tok = GATHER ? tok_slot[rowbase + arow] : arow;
    aptr[i]  = xbf + (size_t)tok * DIM + kc8;
    const int brow = n0 + row;
    b1ptr[i] = W1 + (size_t)brow * DIM + kc8;
    b3ptr[i] = W3 + (size_t)brow * DIM + kc8;
  }

  const int ln = lane & 15, q = lane >> 4;
  const int wm = (w & 1) * 64, wn = (w >> 1) * 64;
  const u16* pa  = sA  + (wm + ln) * 32 + q * 8;
  const u16* pb1 = sB1 + (wn + ln) * 32 + q * 8;
  const u16* pb3 = sB3 + (wn + ln) * 32 + q * 8;

  f4v acc1[4][4] = {};
  f4v acc3[4][4] = {};

  for (int k0 = 0; k0 < DIM; k0 += 32) {
    __syncthreads();
#pragma unroll
    for (int i = 0; i < 2; i++) {
      load_lds16(aptr[i]  + k0, ldsA[i]);
      load_lds16(b1ptr[i] + k0, ldsB1[i]);
      load_lds16(b3ptr[i] + k0, ldsB3[i]);
    }
    __syncthreads();

    s8v af[4];
#pragma unroll
    for (int i = 0; i < 4; i++) af[i] = *(const s8v*)(pa + i * 512);
#pragma unroll
    for (int j = 0; j < 4; j++) {
      s8v bf1 = *(const s8v*)(pb1 + j * 512);
#pragma unroll
      for (int i = 0; i < 4; i++)
        acc1[i][j] = __builtin_amdgcn_mfma_f32_16x16x32_bf16(af[i], bf1, acc1[i][j], 0, 0, 0);
      s8v bf3 = *(const s8v*)(pb3 + j * 512);
#pragma unroll
      for (int i = 0; i < 4; i++)
        acc3[i][j] = __builtin_amdgcn_mfma_f32_16x16x32_bf16(af[i], bf3, acc3[i][j], 0, 0, 0);
    }
  }

  float bb1[4], bb3[4];
#pragma unroll
  for (int j = 0; j < 4; j++) {
    const int col = n0 + wn + j * 16 + ln;
    bb1[j] = B1[col]; bb3[j] = B3[col];
  }
#pragma unroll
  for (int i = 0; i < 4; i++) {
#pragma unroll
    for (int r = 0; r < 4; r++) {
      const int row = m0 + wm + i * 16 + q * 4 + r;  // D: row=quad*4+reg
      if (row >= count) continue;
      u16* ap = act + (size_t)(rowbase + row) * N + n0 + wn;
#pragma unroll
      for (int j = 0; j < 4; j++) {
        float h = acc1[i][j][r] + bb1[j];
        float g = acc3[i][j][r] + bb3[j];
        float sv = 1.f / (1.f + __expf(-h));
        ap[j * 16 + ln] = f2bf(h * sv * g);             // D: col=lane&15
      }
    }
  }
}

// ------------- Down: Y = act @ W2T^T (+b2); scatter-atomic or store ---------
template<bool SCATTER>
__global__ __launch_bounds__(256, 2)
void ffn_down2(const u16* __restrict__ act, int KA,
               const u16* __restrict__ w2t, const float* __restrict__ b2p,
               const int* __restrict__ offsets, const int* __restrict__ tok_slot,
               const float* __restrict__ w_slot, float* __restrict__ out)
{
  int e = 0, rowbase = 0, count = T_TOKENS;
  if constexpr (SCATTER) {
    e = blockIdx.z; rowbase = offsets[e]; count = offsets[e + 1] - rowbase;
  }
  const int m0 = blockIdx.y * 128;
  if (m0 >= count) return;
  const int n0 = blockIdx.x * 128;

  const u16* W2 = w2t + (size_t)e * DIM * KA;   // [DIM][KA] bf16
  const float* B2 = b2p + (size_t)e * DIM;

  __shared__ u16 sA[128 * 32];
  __shared__ u16 sB[128 * 32];

  const int tid = threadIdx.x;
  const int lane = tid & 63;
  const int w = tid >> 6;

  const int kc8 = (lane & 3) * 8;
  const u16* aptr[2]; const u16* bptr[2];
  u16 *ldsA[2], *ldsB[2];
#pragma unroll
  for (int i = 0; i < 2; i++) {
    const int row = i * 64 + w * 16 + (lane >> 2);
    const int ldoff = i * 2048 + w * 512 + lane * 8;
    ldsA[i] = sA + ldoff; ldsB[i] = sB + ldoff;
    int arow = m0 + row; if (arow > count - 1) arow = count - 1;
    aptr[i] = act + (size_t)(rowbase + arow) * KA + kc8;
    bptr[i] = W2 + (size_t)(n0 + row) * KA + kc8;
  }

  const int ln = lane & 15, q = lane >> 4;
  const int wm = (w & 1) * 64, wn = (w >> 1) * 64;
  const u16* pa = sA + (wm + ln) * 32 + q * 8;
  const u16* pb = sB + (wn + ln) * 32 + q * 8;

  f4v acc[4][4] = {};

  for (int k0 = 0; k0 < KA; k0 += 32) {
    __syncthreads();
#pragma unroll
    for (int i = 0; i < 2; i++) {
      load_lds16(aptr[i] + k0, ldsA[i]);
      load_lds16(bptr[i] + k0, ldsB[i]);
    }
    __syncthreads();

    s8v af[4];
#pragma unroll
    for (int i = 0; i < 4; i++) af[i] = *(const s8v*)(pa + i * 512);
#pragma unroll
    for (int j = 0; j < 4; j++) {
      s8v bf = *(const s8v*)(pb + j * 512);
#pragma unroll
      for (int i = 0; i < 4; i++)
        acc[i][j] = __builtin_amdgcn_mfma_f32_16x16x32_bf16(af[i], bf, acc[i][j], 0, 0, 0);
    }
  }

  float bb[4];
#pragma unroll
  for (int j = 0; j < 4; j++) bb[j] = B2[n0 + wn + j * 16 + ln];

#pragma unroll
  for (int i = 0; i < 4; i++) {
#pragma unroll
    for (int r = 0; r < 4; r++) {
      const int row = m0 + wm + i * 16 + q * 4 + r;
      if (row >= count) continue;
      if constexpr (SCATTER) {
        const int slot = rowbase + row;
        const int tok = tok_slot[slot];
        const float wgt = w_slot[slot];
        float* orow = out + (size_t)tok * DIM + n0 + wn;
#pragma unroll
        for (int j = 0; j < 4; j++)
          atomicAdd(&orow[j * 16 + ln], wgt * (acc[i][j][r] + bb[j]));
      } else {
        float* orow = out + (size_t)row * DIM + n0 + wn;
#pragma unroll
        for (int j = 0; j < 4; j++)
          orow[j * 16 + ln] = acc[i][j][r] + bb[j];
      }
    }
  }
}

extern "C" void kernel_launch(void* const* d_in, const int* in_sizes, int n_in,
                              void* d_out, int out_size, void* d_ws, size_t ws_size,
                              hipStream_t stream)
{
  const float* x   = (const float*)d_in[0];
  const float* gw  = (const float*)d_in[1];
  const float* gb  = (const float*)d_in[2];
  const float* w1  = (const float*)d_in[3];
  const float* b1  = (const float*)d_in[4];
  const float* w3  = (const float*)d_in[5];
  const float* b3  = (const float*)d_in[6];
  const float* w2  = (const float*)d_in[7];
  const float* b2  = (const float*)d_in[8];
  const float* sw1 = (const float*)d_in[9];
  const float* sb1 = (const float*)d_in[10];
  const float* sw3 = (const float*)d_in[11];
  const float* sb3 = (const float*)d_in[12];
  const float* sw2 = (const float*)d_in[13];
  const float* sb2 = (const float*)d_in[14];
  float* out = (float*)d_out;

  char* ws = (char*)d_ws;
  size_t off = 0;
  auto alloc = [&](size_t bytes) -> char* {
    off = (off + 255) & ~(size_t)255;
    char* p = ws + off;
    off += bytes;
    return p;
  };
  int*   counts   = (int*)  alloc(NEXP * 4);
  int*   offsets  = (int*)  alloc((NEXP + 1) * 4);
  int*   g_e      = (int*)  alloc((size_t)T_TOKENS * 2 * 4);
  int*   g_r      = (int*)  alloc((size_t)T_TOKENS * 2 * 4);
  float* g_w      = (float*)alloc((size_t)T_TOKENS * 2 * 4);
  int*   tok_slot = (int*)  alloc((size_t)T_TOKENS * 2 * 4);
  float* w_slot   = (float*)alloc((size_t)T_TOKENS * 2 * 4);
  u16*   xbf      = (u16*)  alloc((size_t)T_TOKENS * DIM * 2);
  u16*   w1t      = (u16*)  alloc((size_t)NEXP * INTER * DIM * 2);
  u16*   w3t      = (u16*)  alloc((size_t)NEXP * INTER * DIM * 2);
  u16*   w2t      = (u16*)  alloc((size_t)NEXP * DIM * INTER * 2);
  u16*   sw1t     = (u16*)  alloc((size_t)SINTER * DIM * 2);
  u16*   sw3t     = (u16*)  alloc((size_t)SINTER * DIM * 2);
  u16*   sw2t     = (u16*)  alloc((size_t)DIM * SINTER * 2);
  u16*   A_act    = (u16*)  alloc((size_t)T_TOKENS * 2 * INTER * 2);
  u16*   S_act    = (u16*)  alloc((size_t)T_TOKENS * SINTER * 2);
  (void)ws_size; (void)in_sizes; (void)n_in; (void)out_size;

  hipMemsetAsync(counts, 0, NEXP * 4, stream);

  // ---- weight/activation conversion (bf16, weights transposed to [N][K]) ---
  cvt_x<<<(T_TOKENS * DIM) / (256 * 8), 256, 0, stream>>>(x, xbf);
  transpose_cvt<<<dim3(INTER / 64, DIM / 64, NEXP), 256, 0, stream>>>(w1, w1t, DIM, INTER);
  transpose_cvt<<<dim3(INTER / 64, DIM / 64, NEXP), 256, 0, stream>>>(w3, w3t, DIM, INTER);
  transpose_cvt<<<dim3(DIM / 64, INTER / 64, NEXP), 256, 0, stream>>>(w2, w2t, INTER, DIM);
  transpose_cvt<<<dim3(SINTER / 64, DIM / 64, 1), 256, 0, stream>>>(sw1, sw1t, DIM, SINTER);
  transpose_cvt<<<dim3(SINTER / 64, DIM / 64, 1), 256, 0, stream>>>(sw3, sw3t, DIM, SINTER);
  transpose_cvt<<<dim3(DIM / 64, SINTER / 64, 1), 256, 0, stream>>>(sw2, sw2t, SINTER, DIM);

  // ---- routing ----
  gate_kernel<<<T_TOKENS / 4, 256, 0, stream>>>(x, gw, gb, counts, g_e, g_r, g_w);
  scan_kernel<<<1, 64, 0, stream>>>(counts, offsets);
  scatter_kernel<<<T_TOKENS / 256, 256, 0, stream>>>(g_e, g_r, g_w, offsets, tok_slot, w_slot);

  // ---- shared expert (plain store initializes out) ----
  ffn_up2<false><<<dim3(SINTER / 128, T_TOKENS / 128, 1), 256, 0, stream>>>(
      xbf, sw1t, sb1, sw3t, sb3, SINTER, nullptr, nullptr, S_act);
  ffn_down2<false><<<dim3(DIM / 128, T_TOKENS / 128, 1), 256, 0, stream>>>(
      S_act, SINTER, sw2t, sb2, nullptr, nullptr, nullptr, out);

  // ---- routed experts (compacted GEMMs + weighted atomic scatter) ----
  ffn_up2<true><<<dim3(INTER / 128, T_TOKENS / 128, NEXP), 256, 0, stream>>>(
      xbf, w1t, b1, w3t, b3, INTER, offsets, tok_slot, A_act);
  ffn_down2<true><<<dim3(DIM / 128, T_TOKENS / 128, NEXP), 256, 0, stream>>>(
      A_act, INTER, w2t, b2, offsets, tok_slot, w_slot, out);
}

// Round 3
// 693.426 us; speedup vs baseline: 1.5751x; 1.1203x over previous
//
#include <hip/hip_runtime.h>
#include <cstdint>
#include <cstddef>

#define T_TOKENS 4096
#define DIM      1024
#define INTER    1408
#define NEXP     16
#define SINTER   2816

typedef uint32_t u32;
typedef uint16_t u16;

using s8v = __attribute__((ext_vector_type(8))) short;   // 8 bf16 (4 VGPRs)
using f4v = __attribute__((ext_vector_type(4))) float;   // MFMA accumulator

__device__ __forceinline__ u16 f2bf(float f) {
  u32 u = __float_as_uint(f);
  return (u16)((u + 0x7fffu + ((u >> 16) & 1u)) >> 16);  // RNE
}
__device__ __forceinline__ u32 pack2(float a, float b) {
  return (u32)f2bf(a) | ((u32)f2bf(b) << 16);
}

// async global->LDS, 16B/lane. LDS dest is wave-uniform base + lane*16.
__device__ __forceinline__ void load_lds16(const u16* g, u16* l) {
  __builtin_amdgcn_global_load_lds((const __attribute__((address_space(1))) void*)g,
                                   (__attribute__((address_space(3))) void*)l,
                                   16, 0, 0);
}

// ---------------- x: fp32 -> bf16 (row-major, elementwise) ------------------
__global__ __launch_bounds__(256)
void cvt_x(const float* __restrict__ in, u16* __restrict__ out) {
  const int i = (blockIdx.x * 256 + threadIdx.x) * 8;
  float4 a = *(const float4*)(in + i);
  float4 b = *(const float4*)(in + i + 4);
  uint4 o;
  o.x = pack2(a.x, a.y); o.y = pack2(a.z, a.w);
  o.z = pack2(b.x, b.y); o.w = pack2(b.z, b.w);
  *(uint4*)(out + i) = o;
}

// ------------- weights: [Z][K][N] fp32 -> [Z][N][K] bf16 (transpose) --------
__global__ __launch_bounds__(256)
void transpose_cvt(const float* __restrict__ in, u16* __restrict__ out,
                   int K, int N) {
  const size_t eoff = (size_t)blockIdx.z * K * N;
  const int n0 = blockIdx.x * 64, k0 = blockIdx.y * 64;
  __shared__ u16 t[64][72];   // row stride 144B = 9*16B: 16B-aligned vector reads

  const int tid = threadIdx.x;
  {
    const int r = tid >> 4, c4 = (tid & 15) * 4;
    const float* src = in + eoff + (size_t)k0 * N + n0;
#pragma unroll
    for (int i = 0; i < 4; i++) {
      int row = r + i * 16;
      float4 v = *(const float4*)(src + (size_t)row * N + c4);
      t[c4 + 0][row] = f2bf(v.x);
      t[c4 + 1][row] = f2bf(v.y);
      t[c4 + 2][row] = f2bf(v.z);
      t[c4 + 3][row] = f2bf(v.w);
    }
  }
  __syncthreads();
  {
    const int r = tid >> 3, cc = (tid & 7) * 8;
    u16* dst = out + eoff + (size_t)n0 * K + k0;
#pragma unroll
    for (int i = 0; i < 2; i++) {
      int row = r + i * 32;
      uint4 v = *(const uint4*)&t[row][cc];
      *(uint4*)(dst + (size_t)row * K + cc) = v;
    }
  }
}

// --------- Gate phase 1: logits -> softmax -> per-token top2 (no atomics) ---
// wave per token; lane = s*16 + e  (e = expert, s = k-slice).
// gw[k*16+e] with k = i*4+s  ==> gw[i*64 + lane]: fully coalesced.
__global__ __launch_bounds__(256)
void gate_logits(const float* __restrict__ x, const float* __restrict__ gw,
                 const float* __restrict__ gb,
                 int* __restrict__ g_e, float* __restrict__ g_w)
{
  const int tok  = blockIdx.x * 4 + (threadIdx.x >> 6);
  const int lane = threadIdx.x & 63;
  const int e = lane & 15, s = lane >> 4;
  const float* xr = x + (size_t)tok * DIM;

  float acc = 0.f;
#pragma unroll 8
  for (int i = 0; i < DIM / 4; i++) {
    const int k = i * 4 + s;
    acc = fmaf(xr[k], gw[i * 64 + lane], acc);   // gw[k*NEXP + e]
  }
  acc += __shfl_xor(acc, 16, 64);
  acc += __shfl_xor(acc, 32, 64);
  const float logit = acc + gb[e];

  float mx = logit;
#pragma unroll
  for (int o = 1; o < 16; o <<= 1) mx = fmaxf(mx, __shfl_xor(mx, o, 64));
  float p = __expf(logit - mx);
  float sum = p;
#pragma unroll
  for (int o = 1; o < 16; o <<= 1) sum += __shfl_xor(sum, o, 64);
  p /= sum;

  // top-1
  float m0 = p; int i0 = e;
#pragma unroll
  for (int o = 1; o < 16; o <<= 1) {
    float om = __shfl_xor(m0, o, 64); int oi = __shfl_xor(i0, o, 64);
    if (om > m0 || (om == m0 && oi < i0)) { m0 = om; i0 = oi; }
  }
  // top-2
  float p1 = (e == i0) ? -1.f : p;
  float m1 = p1; int i1 = e;
#pragma unroll
  for (int o = 1; o < 16; o <<= 1) {
    float om = __shfl_xor(m1, o, 64); int oi = __shfl_xor(i1, o, 64);
    if (om > m1 || (om == m1 && oi < i1)) { m1 = om; i1 = oi; }
  }
  if (lane == 0) {
    g_e[tok * 2 + 0] = i0;  g_e[tok * 2 + 1] = i1;
    g_w[tok * 2 + 0] = m0;  g_w[tok * 2 + 1] = m1;
  }
}

// --------- Gate phase 2: single-block scan + deterministic scatter ----------
__global__ __launch_bounds__(256)
void route_build(const int* __restrict__ g_e, const float* __restrict__ g_w,
                 int* __restrict__ offsets,
                 int* __restrict__ tok_slot, float* __restrict__ w_slot)
{
  __shared__ int hist[256][NEXP + 1];   // +1 pad: breaks 16-stride bank aliasing
  __shared__ int base[NEXP + 1];
  const int tid = threadIdx.x;
  const int TPT = T_TOKENS / 256;       // tokens per thread
  const int t0 = tid * TPT;

#pragma unroll
  for (int e = 0; e < NEXP; e++) hist[tid][e] = 0;
  for (int t = t0; t < t0 + TPT; t++) {
    hist[tid][g_e[t * 2 + 0]]++;
    hist[tid][g_e[t * 2 + 1]]++;
  }
  __syncthreads();
  if (tid < NEXP) {                     // per-expert exclusive scan over threads
    int run = 0;
    for (int i = 0; i < 256; i++) { int v = hist[i][tid]; hist[i][tid] = run; run += v; }
    base[tid] = run;                    // total for expert tid
  }
  __syncthreads();
  if (tid == 0) {                       // expert-base exclusive scan
    int run = 0;
#pragma unroll
    for (int e = 0; e < NEXP; e++) { int c = base[e]; base[e] = run; offsets[e] = run; run += c; }
    base[NEXP] = run; offsets[NEXP] = run;
  }
  __syncthreads();
  for (int t = t0; t < t0 + TPT; t++) {
#pragma unroll
    for (int k = 0; k < 2; k++) {
      const int e = g_e[t * 2 + k];
      const int slot = base[e] + hist[tid][e]++;   // prefix cell as running ctr
      tok_slot[slot] = t;
      w_slot[slot] = g_w[t * 2 + k];
    }
  }
}

// ------------- Up: act = silu(X@W1+b1)*(X@W3+b3), 128x128 tile, BK=32 -------
// A: xbf bf16 row-major (gathered rows for routed). B: wT bf16 [N][K] row-major.
template<bool GATHER>
__global__ __launch_bounds__(256, 2)
void ffn_up2(const u16* __restrict__ xbf,
             const u16* __restrict__ w1t, const float* __restrict__ b1p,
             const u16* __restrict__ w3t, const float* __restrict__ b3p,
             int N,
             const int* __restrict__ offsets, const int* __restrict__ tok_slot,
             u16* __restrict__ act)
{
  int e = 0, rowbase = 0, count = T_TOKENS;
  if constexpr (GATHER) {
    e = blockIdx.z; rowbase = offsets[e]; count = offsets[e + 1] - rowbase;
  }
  const int m0 = blockIdx.y * 128;
  if (m0 >= count) return;
  const int n0 = blockIdx.x * 128;

  const u16* W1 = w1t + (size_t)e * N * DIM;
  const u16* W3 = w3t + (size_t)e * N * DIM;
  const float* B1 = b1p + (size_t)e * N;
  const float* B3 = b3p + (size_t)e * N;

  __shared__ u16 sA[128 * 32];
  __shared__ u16 sB1[128 * 32];
  __shared__ u16 sB3[128 * 32];

  const int tid = threadIdx.x;
  const int lane = tid & 63;
  const int w = tid >> 6;

  // staging: instr i covers rows [i*64 + w*16, +16); lane -> (row, 16B k-chunk)
  const int kc8 = (lane & 3) * 8;
  const u16* aptr[2]; const u16* b1ptr[2]; const u16* b3ptr[2];
  u16 *ldsA[2], *ldsB1[2], *ldsB3[2];
#pragma unroll
  for (int i = 0; i < 2; i++) {
    const int row = i * 64 + w * 16 + (lane >> 2);
    const int ldoff = i * 2048 + w * 512 + lane * 8;   // == row*32 + kc8
    ldsA[i] = sA + ldoff; ldsB1[i] = sB1 + ldoff; ldsB3[i] = sB3 + ldoff;
    int arow = m0 + row; if (arow > count - 1) arow = count - 1;  // clamp pads
    const int tok = GATHER ? tok_slot[rowbase + arow] : arow;
    aptr[i]  = xbf + (size_t)tok * DIM + kc8;
    const int brow = n0 + row;
    b1ptr[i] = W1 + (size_t)brow * DIM + kc8;
    b3ptr[i] = W3 + (size_t)brow * DIM + kc8;
  }

  const int ln = lane & 15, q = lane >> 4;
  const int wm = (w & 1) * 64, wn = (w >> 1) * 64;
  const u16* pa  = sA  + (wm + ln) * 32 + q * 8;
  const u16* pb1 = sB1 + (wn + ln) * 32 + q * 8;
  const u16* pb3 = sB3 + (wn + ln) * 32 + q * 8;

  f4v acc1[4][4] = {};
  f4v acc3[4][4] = {};

  for (int k0 = 0; k0 < DIM; k0 += 32) {
    __syncthreads();
#pragma unroll
    for (int i = 0; i < 2; i++) {
      load_lds16(aptr[i]  + k0, ldsA[i]);
      load_lds16(b1ptr[i] + k0, ldsB1[i]);
      load_lds16(b3ptr[i] + k0, ldsB3[i]);
    }
    __syncthreads();

    s8v af[4];
#pragma unroll
    for (int i = 0; i < 4; i++) af[i] = *(const s8v*)(pa + i * 512);
#pragma unroll
    for (int j = 0; j < 4; j++) {
      s8v bf1 = *(const s8v*)(pb1 + j * 512);
#pragma unroll
      for (int i = 0; i < 4; i++)
        acc1[i][j] = __builtin_amdgcn_mfma_f32_16x16x32_bf16(af[i], bf1, acc1[i][j], 0, 0, 0);
      s8v bf3 = *(const s8v*)(pb3 + j * 512);
#pragma unroll
      for (int i = 0; i < 4; i++)
        acc3[i][j] = __builtin_amdgcn_mfma_f32_16x16x32_bf16(af[i], bf3, acc3[i][j], 0, 0, 0);
    }
  }

  float bb1[4], bb3[4];
#pragma unroll
  for (int j = 0; j < 4; j++) {
    const int col = n0 + wn + j * 16 + ln;
    bb1[j] = B1[col]; bb3[j] = B3[col];
  }
#pragma unroll
  for (int i = 0; i < 4; i++) {
#pragma unroll
    for (int r = 0; r < 4; r++) {
      const int row = m0 + wm + i * 16 + q * 4 + r;  // D: row=quad*4+reg
      if (row >= count) continue;
      u16* ap = act + (size_t)(rowbase + row) * N + n0 + wn;
#pragma unroll
      for (int j = 0; j < 4; j++) {
        float h = acc1[i][j][r] + bb1[j];
        float g = acc3[i][j][r] + bb3[j];
        float sv = 1.f / (1.f + __expf(-h));
        ap[j * 16 + ln] = f2bf(h * sv * g);             // D: col=lane&15
      }
    }
  }
}

// ------------- Down: Y = act @ W2T^T (+b2); scatter-atomic or store ---------
template<bool SCATTER>
__global__ __launch_bounds__(256, 2)
void ffn_down2(const u16* __restrict__ act, int KA,
               const u16* __restrict__ w2t, const float* __restrict__ b2p,
               const int* __restrict__ offsets, const int* __restrict__ tok_slot,
               const float* __restrict__ w_slot, float* __restrict__ out)
{
  int e = 0, rowbase = 0, count = T_TOKENS;
  if constexpr (SCATTER) {
    e = blockIdx.z; rowbase = offsets[e]; count = offsets[e + 1] - rowbase;
  }
  const int m0 = blockIdx.y * 128;
  if (m0 >= count) return;
  const int n0 = blockIdx.x * 128;

  const u16* W2 = w2t + (size_t)e * DIM * KA;   // [DIM][KA] bf16
  const float* B2 = b2p + (size_t)e * DIM;

  __shared__ u16 sA[128 * 32];
  __shared__ u16 sB[128 * 32];

  const int tid = threadIdx.x;
  const int lane = tid & 63;
  const int w = tid >> 6;

  const int kc8 = (lane & 3) * 8;
  const u16* aptr[2]; const u16* bptr[2];
  u16 *ldsA[2], *ldsB[2];
#pragma unroll
  for (int i = 0; i < 2; i++) {
    const int row = i * 64 + w * 16 + (lane >> 2);
    const int ldoff = i * 2048 + w * 512 + lane * 8;
    ldsA[i] = sA + ldoff; ldsB[i] = sB + ldoff;
    int arow = m0 + row; if (arow > count - 1) arow = count - 1;
    aptr[i] = act + (size_t)(rowbase + arow) * KA + kc8;
    bptr[i] = W2 + (size_t)(n0 + row) * KA + kc8;
  }

  const int ln = lane & 15, q = lane >> 4;
  const int wm = (w & 1) * 64, wn = (w >> 1) * 64;
  const u16* pa = sA + (wm + ln) * 32 + q * 8;
  const u16* pb = sB + (wn + ln) * 32 + q * 8;

  f4v acc[4][4] = {};

  for (int k0 = 0; k0 < KA; k0 += 32) {
    __syncthreads();
#pragma unroll
    for (int i = 0; i < 2; i++) {
      load_lds16(aptr[i] + k0, ldsA[i]);
      load_lds16(bptr[i] + k0, ldsB[i]);
    }
    __syncthreads();

    s8v af[4];
#pragma unroll
    for (int i = 0; i < 4; i++) af[i] = *(const s8v*)(pa + i * 512);
#pragma unroll
    for (int j = 0; j < 4; j++) {
      s8v bf = *(const s8v*)(pb + j * 512);
#pragma unroll
      for (int i = 0; i < 4; i++)
        acc[i][j] = __builtin_amdgcn_mfma_f32_16x16x32_bf16(af[i], bf, acc[i][j], 0, 0, 0);
    }
  }

  float bb[4];
#pragma unroll
  for (int j = 0; j < 4; j++) bb[j] = B2[n0 + wn + j * 16 + ln];

#pragma unroll
  for (int i = 0; i < 4; i++) {
#pragma unroll
    for (int r = 0; r < 4; r++) {
      const int row = m0 + wm + i * 16 + q * 4 + r;
      if (row >= count) continue;
      if constexpr (SCATTER) {
        const int slot = rowbase + row;
        const int tok = tok_slot[slot];
        const float wgt = w_slot[slot];
        float* orow = out + (size_t)tok * DIM + n0 + wn;
#pragma unroll
        for (int j = 0; j < 4; j++)
          atomicAdd(&orow[j * 16 + ln], wgt * (acc[i][j][r] + bb[j]));
      } else {
        float* orow = out + (size_t)row * DIM + n0 + wn;
#pragma unroll
        for (int j = 0; j < 4; j++)
          orow[j * 16 + ln] = acc[i][j][r] + bb[j];
      }
    }
  }
}

extern "C" void kernel_launch(void* const* d_in, const int* in_sizes, int n_in,
                              void* d_out, int out_size, void* d_ws, size_t ws_size,
                              hipStream_t stream)
{
  const float* x   = (const float*)d_in[0];
  const float* gw  = (const float*)d_in[1];
  const float* gb  = (const float*)d_in[2];
  const float* w1  = (const float*)d_in[3];
  const float* b1  = (const float*)d_in[4];
  const float* w3  = (const float*)d_in[5];
  const float* b3  = (const float*)d_in[6];
  const float* w2  = (const float*)d_in[7];
  const float* b2  = (const float*)d_in[8];
  const float* sw1 = (const float*)d_in[9];
  const float* sb1 = (const float*)d_in[10];
  const float* sw3 = (const float*)d_in[11];
  const float* sb3 = (const float*)d_in[12];
  const float* sw2 = (const float*)d_in[13];
  const float* sb2 = (const float*)d_in[14];
  float* out = (float*)d_out;

  char* ws = (char*)d_ws;
  size_t off = 0;
  auto alloc = [&](size_t bytes) -> char* {
    off = (off + 255) & ~(size_t)255;
    char* p = ws + off;
    off += bytes;
    return p;
  };
  int*   offsets  = (int*)  alloc((NEXP + 1) * 4);
  int*   g_e      = (int*)  alloc((size_t)T_TOKENS * 2 * 4);
  float* g_w      = (float*)alloc((size_t)T_TOKENS * 2 * 4);
  int*   tok_slot = (int*)  alloc((size_t)T_TOKENS * 2 * 4);
  float* w_slot   = (float*)alloc((size_t)T_TOKENS * 2 * 4);
  u16*   xbf      = (u16*)  alloc((size_t)T_TOKENS * DIM * 2);
  u16*   w1t      = (u16*)  alloc((size_t)NEXP * INTER * DIM * 2);
  u16*   w3t      = (u16*)  alloc((size_t)NEXP * INTER * DIM * 2);
  u16*   w2t      = (u16*)  alloc((size_t)NEXP * DIM * INTER * 2);
  u16*   sw1t     = (u16*)  alloc((size_t)SINTER * DIM * 2);
  u16*   sw3t     = (u16*)  alloc((size_t)SINTER * DIM * 2);
  u16*   sw2t     = (u16*)  alloc((size_t)DIM * SINTER * 2);
  u16*   A_act    = (u16*)  alloc((size_t)T_TOKENS * 2 * INTER * 2);
  u16*   S_act    = (u16*)  alloc((size_t)T_TOKENS * SINTER * 2);
  (void)ws_size; (void)in_sizes; (void)n_in; (void)out_size;

  // ---- routing (atomic-free) ----
  gate_logits<<<T_TOKENS / 4, 256, 0, stream>>>(x, gw, gb, g_e, g_w);
  route_build<<<1, 256, 0, stream>>>(g_e, g_w, offsets, tok_slot, w_slot);

  // ---- weight/activation conversion (bf16, weights transposed to [N][K]) ---
  cvt_x<<<(T_TOKENS * DIM) / (256 * 8), 256, 0, stream>>>(x, xbf);
  transpose_cvt<<<dim3(INTER / 64, DIM / 64, NEXP), 256, 0, stream>>>(w1, w1t, DIM, INTER);
  transpose_cvt<<<dim3(INTER / 64, DIM / 64, NEXP), 256, 0, stream>>>(w3, w3t, DIM, INTER);
  transpose_cvt<<<dim3(DIM / 64, INTER / 64, NEXP), 256, 0, stream>>>(w2, w2t, INTER, DIM);
  transpose_cvt<<<dim3(SINTER / 64, DIM / 64, 1), 256, 0, stream>>>(sw1, sw1t, DIM, SINTER);
  transpose_cvt<<<dim3(SINTER / 64, DIM / 64, 1), 256, 0, stream>>>(sw3, sw3t, DIM, SINTER);
  transpose_cvt<<<dim3(DIM / 64, SINTER / 64, 1), 256, 0, stream>>>(sw2, sw2t, SINTER, DIM);

  // ---- shared expert (plain store initializes out) ----
  ffn_up2<false><<<dim3(SINTER / 128, T_TOKENS / 128, 1), 256, 0, stream>>>(
      xbf, sw1t, sb1, sw3t, sb3, SINTER, nullptr, nullptr, S_act);
  ffn_down2<false><<<dim3(DIM / 128, T_TOKENS / 128, 1), 256, 0, stream>>>(
      S_act, SINTER, sw2t, sb2, nullptr, nullptr, nullptr, out);

  // ---- routed experts (compacted GEMMs + weighted atomic scatter) ----
  ffn_up2<true><<<dim3(INTER / 128, T_TOKENS / 128, NEXP), 256, 0, stream>>>(
      xbf, w1t, b1, w3t, b3, INTER, offsets, tok_slot, A_act);
  ffn_down2<true><<<dim3(DIM / 128, T_TOKENS / 128, NEXP), 256, 0, stream>>>(
      A_act, INTER, w2t, b2, offsets, tok_slot, w_slot, out);
}